// Round 7
// baseline (150.226 us; speedup 1.0000x reference)
//
#include <hip/hip_runtime.h>

// ---------------------------------------------------------------------------
// MultiHeadAttention: x(2,2048,768) -> QKV proj -> 12-head causal attn -> proj
// Round 18: 2-phase double-buffered prefetch GEMMs (catalog T3-minimum).
// R4/R5/R6 attn variants all within noise -> attn frozen at R6 (exact-balance,
// no fixup). Both GEMMs were 1-phase (stage -> vmcnt(0) -> barrier -> compute)
// = full DMA round-trip exposed per K-step (m233: ~72% overhead regime).
// Now: K-step 32, LDS double-buffered (gemm1 28 KB -> still 3/CU, gemm2
// 20 KB), schedule = {stage(buf^1, t+1); compute(buf); vmcnt(0); barrier} --
// the stage is issued BEFORE compute so the wait at the end is hidden.
// Chunk swizzle (c ^ ((row>>1)&3)) via swizzled global source + linear LDS
// dest; read-side aliasing max 2-way (free, m136). prep/attn = R6 exact.
// ---------------------------------------------------------------------------

typedef float f32x4 __attribute__((ext_vector_type(4)));
typedef __bf16 bf16x8 __attribute__((ext_vector_type(8)));
typedef unsigned int u32x4 __attribute__((ext_vector_type(4)));

#define D_MODEL 768
#define F3 2304
#define NHEADS 12
#define HEAD 64
#define BB 2
#define TT 2048
#define MROWS (BB*TT)      // 4096
#define KDIM 768
#define LOG2E 1.44269504f
#define NX (MROWS*D_MODEL)
#define NW1 (F3*KDIM)
#define NW2 (D_MODEL*KDIM)

__device__ __forceinline__ unsigned short f2bf(float f) {
    unsigned int u = __float_as_uint(f);
    u += 0x7fffu + ((u >> 16) & 1u);
    return (unsigned short)(u >> 16);
}
__device__ __forceinline__ unsigned int pack2bf(float a, float b) {
    unsigned int ua = __float_as_uint(a), ub = __float_as_uint(b);
    ua += 0x7fffu + ((ua >> 16) & 1u);
    ub += 0x7fffu + ((ub >> 16) & 1u);
    return (ua >> 16) | (ub & 0xffff0000u);
}

__device__ __forceinline__ void async_copy16(unsigned short* lds, const unsigned short* g) {
    __builtin_amdgcn_global_load_lds(
        (const __attribute__((address_space(1))) unsigned int*)(const void*)g,
        (__attribute__((address_space(3))) unsigned int*)(void*)lds,
        16, 0, 0);
}

// ---- fused prep: fp32 -> bf16 for x, W1, W2 (4 elems/thread) --------------
__global__ void prep(const float* __restrict__ x, const float* __restrict__ W1,
                     const float* __restrict__ W2, unsigned short* __restrict__ xb,
                     unsigned short* __restrict__ w1b, unsigned short* __restrict__ w2b) {
    const int i4 = (blockIdx.x * blockDim.x + threadIdx.x) * 4;
    const float* src; unsigned short* dst; int off;
    if (i4 < NX)                  { src = x;  dst = xb;  off = i4; }
    else if (i4 < NX + NW1)       { src = W1; dst = w1b; off = i4 - NX; }
    else if (i4 < NX + NW1 + NW2) { src = W2; dst = w2b; off = i4 - NX - NW1; }
    else return;
    float4 v = *(const float4*)(src + off);
    uint2 o;
    o.x = pack2bf(v.x, v.y);
    o.y = pack2bf(v.z, v.w);
    *(uint2*)(dst + off) = o;
}

// ---- GEMM1: 128x96 tile, K-step 32, 2-phase dbuf prefetch. 768 blocks -----
// XCD band swizzle: xcd = F&7 owns an 8(m) x 12(n) tile band.
__global__ __launch_bounds__(256, 4) void gemm1(
    const unsigned short* __restrict__ A, const unsigned short* __restrict__ Bw,
    const float* __restrict__ bias, int K,
    unsigned short* __restrict__ Qb, unsigned short* __restrict__ Kb,
    unsigned short* __restrict__ VT)
{
    __shared__ unsigned short As[2][128*32];   // 2 x 8 KB
    __shared__ unsigned short Bs[2][96*32];    // 2 x 6 KB
    const int tid  = threadIdx.x;
    const int wave = tid >> 6;
    const int lane = tid & 63;
    const int quad = lane >> 4;
    const int l16  = lane & 15;

    const int F   = blockIdx.x;
    const int xcd = F & 7;
    const int idx = F >> 3;                  // 0..95
    const int bm  = (xcd & 3) * 8 + (idx & 7);    // 0..31
    const int bn  = (xcd >> 2) * 12 + (idx >> 3); // 0..23
    const int m0  = bm * 128;
    const int n0  = bn * 96;
    const int seg = bn >> 3;                 // 0=Q 1=K 2=V (96*8=768)

    const int wm = (wave >> 1) * 64;
    const int wn = (wave & 1) * 48;

    f32x4 acc[4][3] = {};

    const unsigned short* Ablk = A + (size_t)m0 * K;
    const unsigned short* Bblk = Bw + (size_t)n0 * K;

    // staging: slot s holds source chunk c=(s&3)^((r>>1)&3) of row r=s>>2.
    // A: 512 slots (tid, tid+256). B: 384 slots (tid; tid<128: 256+tid).
    const int ra0 = tid >> 2,         ca0 = (tid & 3) ^ ((ra0 >> 1) & 3);
    const int ra1 = (tid + 256) >> 2, ca1 = (tid & 3) ^ ((ra1 >> 1) & 3);
    const int rb1 = (tid + 256) >> 2, cb1 = (tid & 3) ^ ((rb1 >> 1) & 3);

    #define G1_STAGE(buf, k0)                                                   \
        do {                                                                    \
            async_copy16(&As[buf][tid*8],       Ablk + (size_t)ra0*K + (k0) + ca0*8); \
            async_copy16(&As[buf][2048 + tid*8],Ablk + (size_t)ra1*K + (k0) + ca1*8); \
            async_copy16(&Bs[buf][tid*8],       Bblk + (size_t)ra0*K + (k0) + ca0*8); \
            if (tid < 128)                                                      \
                async_copy16(&Bs[buf][2048 + tid*8], Bblk + (size_t)rb1*K + (k0) + cb1*8); \
        } while (0)

    G1_STAGE(0, 0);
    asm volatile("s_waitcnt vmcnt(0)" ::: "memory");
    __syncthreads();

    for (int t = 0; t < 24; ++t) {
        const int cur = t & 1;
        if (t < 23) G1_STAGE(cur ^ 1, (t + 1) * 32);

        const unsigned short* Ab = As[cur];
        const unsigned short* Bb = Bs[cur];
        bf16x8 a[4], b[3];
        #pragma unroll
        for (int i = 0; i < 4; ++i) {
            const int row = wm + i*16 + l16;
            a[i] = *(const bf16x8*)(Ab + row*32 + ((quad ^ ((row >> 1) & 3)) * 8));
        }
        #pragma unroll
        for (int j = 0; j < 3; ++j) {
            const int row = wn + j*16 + l16;
            b[j] = *(const bf16x8*)(Bb + row*32 + ((quad ^ ((row >> 1) & 3)) * 8));
        }
        #pragma unroll
        for (int i = 0; i < 4; ++i)
            #pragma unroll
            for (int j = 0; j < 3; ++j)
                acc[i][j] = __builtin_amdgcn_mfma_f32_16x16x32_bf16(a[i], b[j], acc[i][j], 0, 0, 0);

        asm volatile("s_waitcnt vmcnt(0)" ::: "memory");
        __syncthreads();
    }
    #undef G1_STAGE

    if (seg < 2) {                           // Q or K: (b,h,t,d) scalar stores
        #pragma unroll
        for (int j = 0; j < 3; ++j) {
            const int n = n0 + wn + j*16 + l16;
            const float bv = bias[n];
            const int f = n - seg * 768;
            const int h = f >> 6, d = f & 63;
            #pragma unroll
            for (int i = 0; i < 4; ++i)
                #pragma unroll
                for (int r = 0; r < 4; ++r) {
                    const int m = m0 + wm + i*16 + quad*4 + r;
                    const int b = m >> 11, t = m & 2047;
                    const size_t idxq = (((size_t)(b*NHEADS + h)) * TT + t) * HEAD + d;
                    const float v = acc[i][j][r] + bv;
                    if (seg == 0) Qb[idxq] = f2bf(v * (0.125f * LOG2E));
                    else          Kb[idxq] = f2bf(v);
                }
        }
    } else {                                 // V: write V^T (b,h,d,t), 8B packed
        #pragma unroll
        for (int j = 0; j < 3; ++j) {
            const int n = n0 + wn + j*16 + l16;
            const float bv = bias[n];
            const int f = n - 1536;
            const int h = f >> 6, d = f & 63;
            #pragma unroll
            for (int i = 0; i < 4; ++i) {
                const int m = m0 + wm + i*16 + quad*4;
                const int b = m >> 11, t = m & 2047;
                uint2 pk;
                pk.x = pack2bf(acc[i][j][0] + bv, acc[i][j][1] + bv);
                pk.y = pack2bf(acc[i][j][2] + bv, acc[i][j][3] + bv);
                *(uint2*)(VT + ((size_t)(b*NHEADS + h) * HEAD + d) * TT + t) = pk;
            }
        }
    }
}

// ---- GEMM2: 64x96 tile, K-step 32, 2-phase dbuf prefetch. 512 blocks ------
// XCD band swizzle: xcd owns a 16(m) x 4(n) tile band.
__global__ __launch_bounds__(256, 4) void gemm2(
    const unsigned short* __restrict__ A, const unsigned short* __restrict__ Bw,
    const float* __restrict__ bias, int K, float* __restrict__ Cout)
{
    __shared__ unsigned short As[2][64*32];    // 2 x 4 KB
    __shared__ unsigned short Bs[2][96*32];    // 2 x 6 KB
    const int tid  = threadIdx.x;
    const int wave = tid >> 6;
    const int lane = tid & 63;
    const int quad = lane >> 4;
    const int l16  = lane & 15;

    const int F   = blockIdx.x;
    const int xcd = F & 7;
    const int idx = F >> 3;                  // 0..63
    const int m0  = ((xcd & 3) * 16 + (idx & 15)) * 64;   // 64 m-tiles
    const int n0  = ((xcd >> 2) * 4 + (idx >> 4)) * 96;   // 8 n-tiles

    const int wm = (wave >> 1) * 32;
    const int wn = (wave & 1) * 48;

    f32x4 acc[2][3] = {};

    const unsigned short* Ablk = A + (size_t)m0 * K;
    const unsigned short* Bblk = Bw + (size_t)n0 * K;

    const int ra0 = tid >> 2,         ca0 = (tid & 3) ^ ((ra0 >> 1) & 3);
    const int rb1 = (tid + 256) >> 2, cb1 = (tid & 3) ^ ((rb1 >> 1) & 3);

    #define G2_STAGE(buf, k0)                                                   \
        do {                                                                    \
            async_copy16(&As[buf][tid*8],  Ablk + (size_t)ra0*K + (k0) + ca0*8); \
            async_copy16(&Bs[buf][tid*8],  Bblk + (size_t)ra0*K + (k0) + ca0*8); \
            if (tid < 128)                                                      \
                async_copy16(&Bs[buf][2048 + tid*8], Bblk + (size_t)rb1*K + (k0) + cb1*8); \
        } while (0)

    G2_STAGE(0, 0);
    asm volatile("s_waitcnt vmcnt(0)" ::: "memory");
    __syncthreads();

    for (int t = 0; t < 24; ++t) {
        const int cur = t & 1;
        if (t < 23) G2_STAGE(cur ^ 1, (t + 1) * 32);

        const unsigned short* Ab = As[cur];
        const unsigned short* Bb = Bs[cur];
        bf16x8 a[2], b[3];
        #pragma unroll
        for (int i = 0; i < 2; ++i) {
            const int row = wm + i*16 + l16;
            a[i] = *(const bf16x8*)(Ab + row*32 + ((quad ^ ((row >> 1) & 3)) * 8));
        }
        #pragma unroll
        for (int j = 0; j < 3; ++j) {
            const int row = wn + j*16 + l16;
            b[j] = *(const bf16x8*)(Bb + row*32 + ((quad ^ ((row >> 1) & 3)) * 8));
        }
        #pragma unroll
        for (int i = 0; i < 2; ++i)
            #pragma unroll
            for (int j = 0; j < 3; ++j)
                acc[i][j] = __builtin_amdgcn_mfma_f32_16x16x32_bf16(a[i], b[j], acc[i][j], 0, 0, 0);

        asm volatile("s_waitcnt vmcnt(0)" ::: "memory");
        __syncthreads();
    }
    #undef G2_STAGE

    #pragma unroll
    for (int j = 0; j < 3; ++j) {
        const int n = n0 + wn + j*16 + l16;
        const float bv = bias[n];
        #pragma unroll
        for (int i = 0; i < 2; ++i)
            #pragma unroll
            for (int r = 0; r < 4; ++r) {
                const int m = m0 + wm + i*16 + quad*4 + r;
                Cout[(size_t)m * D_MODEL + n] = acc[i][j][r] + bv;
            }
    }
}

// ---- flash attention (causal), exact-balance pair jobs, k-split waves -----
// identical to round 17. 768 blocks, 32 KB LDS -> 3/CU. Job j: q-tiles t=j
// then 63-j; 17 iters for every j. Waves k-split the 128-k tile; O/l
// partials in registers; one LDS combine per segment; in-register P PV.
__global__ __launch_bounds__(256, 3) void attn(
    const unsigned short* __restrict__ Qb, const unsigned short* __restrict__ Kb,
    const unsigned short* __restrict__ VT, unsigned short* __restrict__ Ob)
{
    __shared__ unsigned short Ks[128*64];   // 16 KB (combine: waves 1,2 O-buf)
    __shared__ unsigned short Vt[64*128];   // 16 KB (combine: wave 3 O-buf + l)

    const int tid  = threadIdx.x;
    const int wave = tid >> 6;
    const int lane = tid & 63;
    const int quad = lane >> 4;
    const int l16  = lane & 15;

    const int F    = blockIdx.y * 32 + blockIdx.x;   // flat dispatch id
    const int xcd  = F & 7;
    const int slot = F >> 3;                          // 0..95
    const int bh   = xcd * 3 + (slot >> 5);           // 3 heads per XCD
    const int j    = slot & 31;                       // pair-job id 0..31
    const size_t hbase = (size_t)bh * TT * HEAD;

    // DMA source offsets (thread tid fills LDS chunk tid*8):
    const int krow = tid >> 3;
    const int kchunk = ((tid & 7) ^ (krow & 7)) * 8;
    const int vrow = tid >> 4;
    const int vchunk = ((tid & 15) ^ vrow) * 8;

    #pragma unroll 1
    for (int seg = 0; seg < 2; ++seg) {
        const int t   = seg ? (63 - j) : j;     // q-tile (32 rows)
        const int nkt = (t >> 2) + 1;           // KV tiles to stream
        const int q0  = t * 32;

        // Q B-frags: qreg[qs][kc2], lane l16 = q col, slots d = kc2*32+quad*8+.
        bf16x8 qreg[2][2];
        #pragma unroll
        for (int qs = 0; qs < 2; ++qs) {
            const unsigned short* qp = Qb + hbase + (size_t)(q0 + qs*16 + l16) * HEAD + quad*8;
            qreg[qs][0] = *(const bf16x8*)(qp);
            qreg[qs][1] = *(const bf16x8*)(qp + 32);
        }

        f32x4 oacc[2][4] = {};    // [qs][dt]: q = q0+qs*16+quad*4+r, d = dt*16+l16
        float lst[2] = {0.f, 0.f};

        for (int kt = 0; kt < nkt; ++kt) {
            __syncthreads();   // prev consumers (incl. prev combine) done

            const unsigned short* ksrc = Kb + hbase + (size_t)kt * 128 * HEAD;
            #pragma unroll
            for (int ii = 0; ii < 4; ++ii)
                async_copy16(Ks + ii*2048 + tid*8,
                             ksrc + (size_t)(ii*32 + krow) * 64 + kchunk);
            #pragma unroll
            for (int ii = 0; ii < 4; ++ii)
                async_copy16(Vt + ii*2048 + tid*8,
                             VT + hbase + (size_t)(ii*16 + vrow) * TT + kt*128 + vchunk);
            asm volatile("s_waitcnt vmcnt(0)" ::: "memory");
            __syncthreads();

            // S^T tiles s[n][qs]: A = K rows (wave's 32-k slice), B = Q
            f32x4 s[2][2] = {};
            #pragma unroll
            for (int kc2 = 0; kc2 < 2; ++kc2) {
                const int pos = ((kc2*4 + quad) ^ (l16 & 7)) * 8;
                #pragma unroll
                for (int n = 0; n < 2; ++n) {
                    const bf16x8 ak = *(const bf16x8*)(Ks + (wave*32 + n*16 + l16)*64 + pos);
                    #pragma unroll
                    for (int qs = 0; qs < 2; ++qs)
                        s[n][qs] = __builtin_amdgcn_mfma_f32_16x16x32_bf16(ak, qreg[qs][kc2], s[n][qs], 0, 0, 0);
                }
            }

            // causal mask: only the diagonal KV tile
            if (kt == (t >> 2)) {
                const int kq = kt*128 + wave*32 + quad*4;
                #pragma unroll
                for (int n = 0; n < 2; ++n)
                    #pragma unroll
                    for (int qs = 0; qs < 2; ++qs)
                        #pragma unroll
                        for (int r = 0; r < 4; ++r)
                            if (kq + n*16 + r > q0 + qs*16 + l16) s[n][qs][r] = -1e30f;
            }

            // softmax numerators, fixed max (log2e folded into Q); pack pairs
            uint2 pck[2][2];
            #pragma unroll
            for (int n = 0; n < 2; ++n)
                #pragma unroll
                for (int qs = 0; qs < 2; ++qs) {
                    const float p0 = exp2f(s[n][qs][0]);
                    const float p1 = exp2f(s[n][qs][1]);
                    const float p2 = exp2f(s[n][qs][2]);
                    const float p3 = exp2f(s[n][qs][3]);
                    lst[qs] += (p0 + p1) + (p2 + p3);
                    pck[n][qs].x = pack2bf(p0, p1);
                    pck[n][qs].y = pack2bf(p2, p3);
                }

            // O += P V over wave's 32-k slice. A-frag slots: j<4 -> k=4q+j,
            // j>=4 -> k=16+4q+(j-4). B(V) read to match: chunks g1, g1+2.
            bf16x8 ap[2];
            #pragma unroll
            for (int qs = 0; qs < 2; ++qs) {
                u32x4 pw = {pck[0][qs].x, pck[0][qs].y, pck[1][qs].x, pck[1][qs].y};
                ap[qs] = __builtin_bit_cast(bf16x8, pw);
            }
            const int g1 = wave*4 + (quad >> 1);
            #pragma unroll
            for (int dt = 0; dt < 4; ++dt) {
                const unsigned short* vr = Vt + (dt*16 + l16)*128;
                const int c1 = ((g1     ^ l16) * 8) + (quad & 1) * 4;
                const int c2 = (((g1+2) ^ l16) * 8) + (quad & 1) * 4;
                const uint2 lo = *(const uint2*)(vr + c1);
                const uint2 hi = *(const uint2*)(vr + c2);
                u32x4 vv = {lo.x, lo.y, hi.x, hi.y};
                const bf16x8 bv = __builtin_bit_cast(bf16x8, vv);
                #pragma unroll
                for (int qs = 0; qs < 2; ++qs)
                    oacc[qs][dt] = __builtin_amdgcn_mfma_f32_16x16x32_bf16(ap[qs], bv, oacc[qs][dt], 0, 0, 0);
            }
        }

        // cross-quad reduce l (per-lane q = qs*16+l16)
        #pragma unroll
        for (int qs = 0; qs < 2; ++qs) {
            lst[qs] += __shfl_xor(lst[qs], 16);
            lst[qs] += __shfl_xor(lst[qs], 32);
        }

        // ---- cross-wave combine via LDS (aliases Ks/Vt) + epilogue ----
        __syncthreads();   // all waves done reading Ks/Vt
        {
            float* O1 = (float*)Ks;           // wave 1
            float* O2 = (float*)Ks + 2048;    // wave 2
            float* O3 = (float*)Vt;           // wave 3
            float* Lb = (float*)Vt + 2048;    // 96 floats l-partials
            if (wave != 0) {
                float* ob = (wave == 1) ? O1 : (wave == 2) ? O2 : O3;
                #pragma unroll
                for (int qs = 0; qs < 2; ++qs)
                    #pragma unroll
                    for (int dt = 0; dt < 4; ++dt)
                        #pragma unroll
                        for (int r = 0; r < 4; ++r)
                            ob[(qs*16 + quad*4 + r)*64 + dt*16 + l16] = oacc[qs][dt][r];
                if (lane < 16) {
                    Lb[(wave-1)*32 + l16]      = lst[0];
                    Lb[(wave-1)*32 + 16 + l16] = lst[1];
                }
            }
            __syncthreads();
            if (wave == 0) {
                float linv[2], lr[2][4];
                #pragma unroll
                for (int qs = 0; qs < 2; ++qs) {
                    const float lt = lst[qs] + Lb[qs*16 + l16] + Lb[32 + qs*16 + l16]
                                             + Lb[64 + qs*16 + l16];
                    linv[qs] = 1.0f / lt;
                }
                #pragma unroll
                for (int qs = 0; qs < 2; ++qs)
                    #pragma unroll
                    for (int r = 0; r < 4; ++r)
                        lr[qs][r] = __shfl(linv[qs], quad*4 + r);
                const int b = bh / NHEADS, h = bh % NHEADS;
                #pragma unroll
                for (int qs = 0; qs < 2; ++qs)
                    #pragma unroll
                    for (int r = 0; r < 4; ++r) {
                        const int m = b * TT + q0 + qs*16 + quad*4 + r;
                        unsigned short* dst = Ob + (size_t)m * D_MODEL + h*HEAD;
                        #pragma unroll
                        for (int dt = 0; dt < 4; ++dt) {
                            const int idx = (qs*16 + quad*4 + r)*64 + dt*16 + l16;
                            const float v = oacc[qs][dt][r] + O1[idx] + O2[idx] + O3[idx];
                            dst[dt*16 + l16] = f2bf(v * lr[qs][r]);
                        }
                    }
            }
        }
    }
}

// ---------------------------------------------------------------------------
extern "C" void kernel_launch(void* const* d_in, const int* in_sizes, int n_in,
                              void* d_out, int out_size, void* d_ws, size_t ws_size,
                              hipStream_t stream) {
    const float* x  = (const float*)d_in[0];
    const float* W1 = (const float*)d_in[1];
    const float* b1 = (const float*)d_in[2];
    const float* W2 = (const float*)d_in[3];
    const float* b2 = (const float*)d_in[4];
    float* out = (float*)d_out;

    unsigned short* ws = (unsigned short*)d_ws;
    unsigned short* xb  = ws;                                   // 4096*768
    unsigned short* w1b = xb  + (size_t)NX;                     // 2304*768
    unsigned short* w2b = w1b + (size_t)NW1;                    // 768*768
    unsigned short* Qb  = w2b + (size_t)NW2;                    // 24*2048*64
    unsigned short* Kb  = Qb + (size_t)BB*NHEADS*TT*HEAD;
    unsigned short* VT  = Kb + (size_t)BB*NHEADS*TT*HEAD;       // (b,h,d,t)
    unsigned short* Ob  = VT + (size_t)BB*NHEADS*TT*HEAD;       // 4096*768

    prep<<<((NX + NW1 + NW2)/4 + 255)/256, 256, 0, stream>>>(
        x, W1, W2, xb, w1b, w2b);

    gemm1<<<768, 256, 0, stream>>>(
        xb, w1b, b1, KDIM, Qb, Kb, VT);

    attn<<<dim3(32, BB*NHEADS), 256, 0, stream>>>(Qb, Kb, VT, Ob);

    gemm2<<<512, 256, 0, stream>>>(
        Ob, w2b, b2, KDIM, out);
}